// Round 5
// baseline (145.508 us; speedup 1.0000x reference)
//
#include <hip/hip_runtime.h>
#include <stdint.h>

#define B_ 8
#define C_ 256
#define O_ 256
#define HW_ 4096

typedef _Float16 f16x8 __attribute__((ext_vector_type(8)));
typedef __attribute__((ext_vector_type(4))) float f32x4;

// ---------- prep: x (NCHW f32) -> xT (NHWC fp16, relu applied) ----------
__global__ __launch_bounds__(256) void k_nhwc(const float* __restrict__ x,
                                              _Float16* __restrict__ xT) {
    int bh = blockIdx.x;
    int b = bh & 7, h = bh >> 3;
    int t = threadIdx.x, px = t & 63, wg = t >> 6;
#pragma unroll
    for (int i = 0; i < 4; ++i) {
        int c0 = i * 64 + wg * 16;
        f16x8 va, vb;
#pragma unroll
        for (int j = 0; j < 8; ++j) {
            float f0 = x[((size_t)(b * C_ + c0 + j)) * HW_ + h * 64 + px];
            float f1 = x[((size_t)(b * C_ + c0 + 8 + j)) * HW_ + h * 64 + px];
            va[j] = (_Float16)fmaxf(f0, 0.f);
            vb[j] = (_Float16)fmaxf(f1, 0.f);
        }
        _Float16* dst = xT + ((size_t)((b * 64 + h) * 64 + px)) * C_ + c0;
        *reinterpret_cast<f16x8*>(dst) = va;
        *reinterpret_cast<f16x8*>(dst + 8) = vb;
    }
}

// ---------- prep: w_def -> fp16 MFMA A-frags [k2][q8][mfg16][lane64][8] ----------
__global__ void k_prep_wdef(const float* __restrict__ w_def, _Float16* __restrict__ wfrag) {
    int idx = blockIdx.x * 256 + threadIdx.x;
    if (idx >= 9 * 8 * 16 * 64) return;
    int lane = idx & 63;
    int mfg = (idx >> 6) & 15;
    int ccc = (idx >> 10) & 7;
    int k2 = idx >> 13;
    int o = mfg * 16 + (lane & 15);
    int cb = ccc * 32 + (lane >> 4) * 8;
    f16x8 pk;
#pragma unroll
    for (int j = 0; j < 8; ++j)
        pk[j] = (_Float16)w_def[(size_t)(o * C_ + cb + j) * 9 + k2];
    *reinterpret_cast<f16x8*>(wfrag + (size_t)idx * 8) = pk;
}

// ---------- prep: w_off -> fp16 MFMA A-frags (M pad 18->32) ----------
__global__ void k_prep_woffrag(const float* __restrict__ w_off, _Float16* __restrict__ wfr) {
    int idx = blockIdx.x * 256 + threadIdx.x;
    if (idx >= 9 * 8 * 2 * 64) return;
    int lane = idx & 63;
    int mfg = (idx >> 6) & 1;
    int ccc = (idx >> 7) & 7;
    int k2 = idx >> 10;
    int o = mfg * 16 + (lane & 15);
    int cb = ccc * 32 + (lane >> 4) * 8;
    f16x8 pk;
#pragma unroll
    for (int j = 0; j < 8; ++j)
        pk[j] = (o < 18) ? (_Float16)w_off[(size_t)(o * C_ + cb + j) * 9 + k2] : (_Float16)0.f;
    *reinterpret_cast<f16x8*>(wfr + (size_t)idx * 8) = pk;
}

// ---------- offset conv via MFMA, no LDS ----------
__global__ __launch_bounds__(256) void k_offconv4(const _Float16* __restrict__ xT,
                                                  const _Float16* __restrict__ wofr,
                                                  const float* __restrict__ b_off,
                                                  float* __restrict__ offs) {
    int bh = blockIdx.x;
    int b = bh & 7, h = bh >> 3;
    int tid = threadIdx.x, lane = tid & 63, wm = tid >> 6;
    int px = wm * 16 + (lane & 15);
    int chl = (lane >> 4) * 8;
    f32x4 acc0 = (f32x4){0.f, 0.f, 0.f, 0.f};
    f32x4 acc1 = (f32x4){0.f, 0.f, 0.f, 0.f};
    const _Float16* xb = xT + (size_t)b * HW_ * C_;
    for (int k2 = 0; k2 < 9; ++k2) {
        int y = h + k2 / 3 - 1;
        int xs = px + k2 % 3 - 1;
        bool v = ((unsigned)y < 64u) && ((unsigned)xs < 64u);
        int yc = y < 0 ? 0 : (y > 63 ? 63 : y);
        int xc = xs < 0 ? 0 : (xs > 63 ? 63 : xs);
        const _Float16* xp = xb + (size_t)(yc * 64 + xc) * C_ + chl;
#pragma unroll
        for (int q = 0; q < 8; ++q) {
            f16x8 bf = *reinterpret_cast<const f16x8*>(xp + q * 32);
            if (!v) bf = (f16x8)(_Float16)0.f;
            const f16x8* wp = reinterpret_cast<const f16x8*>(wofr) +
                              (size_t)((k2 * 8 + q) * 2) * 64 + lane;
            acc0 = __builtin_amdgcn_mfma_f32_16x16x32_f16(wp[0], bf, acc0, 0, 0, 0);
            acc1 = __builtin_amdgcn_mfma_f32_16x16x32_f16(wp[64], bf, acc1, 0, 0, 0);
        }
    }
#pragma unroll
    for (int r = 0; r < 4; ++r) {
        int oc = (lane >> 4) * 4 + r;
        offs[(((size_t)b * 18 + oc) * 64 + h) * 64 + px] = acc0[r] + b_off[oc];
    }
#pragma unroll
    for (int r = 0; r < 4; ++r) {
        int oc = 16 + (lane >> 4) * 4 + r;
        if (oc < 18)
            offs[(((size_t)b * 18 + oc) * 64 + h) * 64 + px] = acc1[r] + b_off[oc];
    }
}

// ---------- fused bilinear gather + MFMA GEMM: N=32 half-row blocks, 4 blocks/CU ----------
// Block = (b, h, half): M=256, N=32 pixels, K=2304. grid=1024, b=blk&7 (XCD-locality).
__global__ __launch_bounds__(256, 4) void k_deform5(const _Float16* __restrict__ xT,
                                                    const _Float16* __restrict__ wfrag,
                                                    const float* __restrict__ offs,
                                                    float* __restrict__ out) {
    int blk = blockIdx.x;
    int b = blk & 7;
    int rh = blk >> 3;        // 0..127
    int h = rh >> 1;
    int px0 = (rh & 1) * 32;
    int tid = threadIdx.x, lane = tid & 63, wm = tid >> 6;

    __shared__ float s_py[9][32], s_px[9][32];
    __shared__ __align__(16) _Float16 s_samp[2][32 * 64];

    // geometry for the 32 pixels of this half-row
    for (int idx = tid; idx < 288; idx += 256) {
        int k2 = idx >> 5, p = idx & 31;
        float dy = offs[(((size_t)b * 18 + k2 * 2 + 0) * 64 + h) * 64 + px0 + p];
        float dx = offs[(((size_t)b * 18 + k2 * 2 + 1) * 64 + h) * 64 + px0 + p];
        s_py[k2][p] = (float)(h - 1 + k2 / 3) + dy;
        s_px[k2][p] = (float)(px0 + p - 1 + k2 % 3) + dx;
    }
    __syncthreads();

    f32x4 acc[4][2];
#pragma unroll
    for (int i = 0; i < 4; ++i)
#pragma unroll
        for (int j = 0; j < 2; ++j) acc[i][j] = (f32x4){0.f, 0.f, 0.f, 0.f};

    const _Float16* xb = xT + (size_t)b * HW_ * C_;

    // gather role of this thread: pixel p (0..31), 8-ch chunk q (0..7)
    int gp = tid & 31, gq = tid >> 5;

    _Float16 hw00, hw01, hw10, hw11;
    int i00, i01, i10, i11;
    f16x8 g0, g1, g2, g3;

#define GEOM(K2)                                                                  \
    {                                                                             \
        float py = s_py[K2][gp], pxx = s_px[K2][gp];                              \
        float y0f = floorf(py), x0f = floorf(pxx);                                \
        float wy = py - y0f, wx = pxx - x0f;                                      \
        int y0 = (int)y0f, x0 = (int)x0f;                                         \
        float w00 = (1.f - wy) * (1.f - wx), w01 = (1.f - wy) * wx;               \
        float w10 = wy * (1.f - wx), w11 = wy * wx;                               \
        bool vy0 = (unsigned)y0 < 64u, vy1 = (unsigned)(y0 + 1) < 64u;            \
        bool vx0 = (unsigned)x0 < 64u, vx1 = (unsigned)(x0 + 1) < 64u;            \
        if (!(vy0 && vx0)) w00 = 0.f;                                             \
        if (!(vy0 && vx1)) w01 = 0.f;                                             \
        if (!(vy1 && vx0)) w10 = 0.f;                                             \
        if (!(vy1 && vx1)) w11 = 0.f;                                             \
        hw00 = (_Float16)w00; hw01 = (_Float16)w01;                               \
        hw10 = (_Float16)w10; hw11 = (_Float16)w11;                               \
        int y0c = y0 < 0 ? 0 : (y0 > 63 ? 63 : y0);                               \
        int y1c = (y0 + 1) < 0 ? 0 : ((y0 + 1) > 63 ? 63 : (y0 + 1));             \
        int x0c = x0 < 0 ? 0 : (x0 > 63 ? 63 : x0);                               \
        int x1c = (x0 + 1) < 0 ? 0 : ((x0 + 1) > 63 ? 63 : (x0 + 1));             \
        i00 = (y0c * 64 + x0c) * C_; i01 = (y0c * 64 + x1c) * C_;                 \
        i10 = (y1c * 64 + x0c) * C_; i11 = (y1c * 64 + x1c) * C_;                 \
    }

#define ISSUE(S)                                                                  \
    {                                                                             \
        int ch0 = ((S) & 3) * 64 + gq * 8;                                        \
        g0 = *reinterpret_cast<const f16x8*>(xb + i00 + ch0);                     \
        g1 = *reinterpret_cast<const f16x8*>(xb + i01 + ch0);                     \
        g2 = *reinterpret_cast<const f16x8*>(xb + i10 + ch0);                     \
        g3 = *reinterpret_cast<const f16x8*>(xb + i11 + ch0);                     \
    }

#define PACK(BUF)                                                                 \
    {                                                                             \
        f16x8 pk = g0 * hw00 + g1 * hw01 + g2 * hw10 + g3 * hw11;                 \
        int slot = (gq ^ (gp & 7)) & 7;                                           \
        *reinterpret_cast<f16x8*>(&s_samp[BUF][gp * 64 + slot * 8]) = pk;         \
    }

    // prologue: gather+pack step 0 into buf 0
    GEOM(0);
    ISSUE(0);
    PACK(0);
    asm volatile("s_waitcnt lgkmcnt(0)" ::: "memory");
    __builtin_amdgcn_s_barrier();

#pragma unroll 2
    for (int s = 0; s < 36; ++s) {
        // A-frag loads for step s (oldest vmem in this iteration)
        f16x8 Ac[2][4];
        const f16x8* wf = reinterpret_cast<const f16x8*>(wfrag) +
                          (size_t)(s * 32 + wm * 4) * 64 + lane;
#pragma unroll
        for (int kk = 0; kk < 2; ++kk)
#pragma unroll
            for (int mf = 0; mf < 4; ++mf)
                Ac[kk][mf] = wf[(size_t)(kk * 16 + mf) * 64];

        // B frags for step s from LDS
        f16x8 bfr[2][2];
#pragma unroll
        for (int kk = 0; kk < 2; ++kk)
#pragma unroll
            for (int nf = 0; nf < 2; ++nf) {
                int n = nf * 16 + (lane & 15);
                int oct = kk * 4 + (lane >> 4);
                int slot = (oct ^ (n & 7)) & 7;
                bfr[kk][nf] = *reinterpret_cast<const f16x8*>(&s_samp[s & 1][n * 64 + slot * 8]);
            }

        // gathers for step s+1 (younger than A-loads: MFMA's vmcnt wait skips them)
        int nxt = s + 1;
        if (nxt < 36) {
            if ((nxt & 3) == 0) GEOM(nxt >> 2);
            ISSUE(nxt);
        }

        // MFMA: waits on A-loads (vmcnt~4) + bfr (lgkm), gathers stay in flight
#pragma unroll
        for (int kk = 0; kk < 2; ++kk)
#pragma unroll
            for (int mf = 0; mf < 4; ++mf)
#pragma unroll
                for (int nf = 0; nf < 2; ++nf)
                    acc[mf][nf] = __builtin_amdgcn_mfma_f32_16x16x32_f16(
                        Ac[kk][mf], bfr[kk][nf], acc[mf][nf], 0, 0, 0);

        if (nxt < 36) {
            PACK(nxt & 1);  // waits vmcnt(0): only gathers outstanding, hidden under MFMAs
        }
        asm volatile("s_waitcnt lgkmcnt(0)" ::: "memory");  // ds_write + ds_read drained
        __builtin_amdgcn_s_barrier();
    }

    float* op = out + (size_t)b * O_ * HW_ + h * 64 + px0;
#pragma unroll
    for (int mf = 0; mf < 4; ++mf)
#pragma unroll
        for (int nf = 0; nf < 2; ++nf)
#pragma unroll
            for (int r = 0; r < 4; ++r) {
                int o = wm * 64 + mf * 16 + (lane >> 4) * 4 + r;
                int w = nf * 16 + (lane & 15);
                op[(size_t)o * HW_ + w] = acc[mf][nf][r];
            }
}

extern "C" void kernel_launch(void* const* d_in, const int* in_sizes, int n_in,
                              void* d_out, int out_size, void* d_ws, size_t ws_size,
                              hipStream_t stream) {
    const float* x = (const float*)d_in[0];
    const float* w_off = (const float*)d_in[1];
    const float* b_off = (const float*)d_in[2];
    const float* w_def = (const float*)d_in[3];
    float* out = (float*)d_out;
    char* ws = (char*)d_ws;

    float* offs = (float*)ws;                                            // 2,359,296 B
    _Float16* xT = (_Float16*)(ws + 2359296);                            // 16,777,216 B
    _Float16* wfrag = (_Float16*)(ws + 2359296 + 16777216);              // 1,179,648 B
    _Float16* wofr = (_Float16*)(ws + 2359296 + 16777216 + 1179648);     // 147,456 B

    k_nhwc<<<512, 256, 0, stream>>>(x, xT);
    k_prep_wdef<<<288, 256, 0, stream>>>(w_def, wfrag);
    k_prep_woffrag<<<36, 256, 0, stream>>>(w_off, wofr);
    k_offconv4<<<512, 256, 0, stream>>>(xT, wofr, b_off, offs);
    k_deform5<<<1024, 256, 0, stream>>>(xT, wfrag, offs, out);
}

// Round 6
// 106.635 us; speedup vs baseline: 1.3645x; 1.3645x over previous
//
#include <hip/hip_runtime.h>
#include <stdint.h>

#define B_ 8
#define C_ 256
#define O_ 256
#define HW_ 4096

typedef _Float16 f16x8 __attribute__((ext_vector_type(8)));
typedef __attribute__((ext_vector_type(4))) float f32x4;

// ---------- prep: x (NCHW f32) -> xT (NHWC fp16, relu applied) ----------
__global__ __launch_bounds__(256) void k_nhwc(const float* __restrict__ x,
                                              _Float16* __restrict__ xT) {
    int bh = blockIdx.x;
    int b = bh & 7, h = bh >> 3;
    int t = threadIdx.x, px = t & 63, wg = t >> 6;
#pragma unroll
    for (int i = 0; i < 4; ++i) {
        int c0 = i * 64 + wg * 16;
        f16x8 va, vb;
#pragma unroll
        for (int j = 0; j < 8; ++j) {
            float f0 = x[((size_t)(b * C_ + c0 + j)) * HW_ + h * 64 + px];
            float f1 = x[((size_t)(b * C_ + c0 + 8 + j)) * HW_ + h * 64 + px];
            va[j] = (_Float16)fmaxf(f0, 0.f);
            vb[j] = (_Float16)fmaxf(f1, 0.f);
        }
        _Float16* dst = xT + ((size_t)((b * 64 + h) * 64 + px)) * C_ + c0;
        *reinterpret_cast<f16x8*>(dst) = va;
        *reinterpret_cast<f16x8*>(dst + 8) = vb;
    }
}

// ---------- prep: w_def -> fp16 MFMA A-frags [k2][q8][mfg16][lane64][8] ----------
__global__ void k_prep_wdef(const float* __restrict__ w_def, _Float16* __restrict__ wfrag) {
    int idx = blockIdx.x * 256 + threadIdx.x;
    if (idx >= 9 * 8 * 16 * 64) return;
    int lane = idx & 63;
    int mfg = (idx >> 6) & 15;
    int ccc = (idx >> 10) & 7;
    int k2 = idx >> 13;
    int o = mfg * 16 + (lane & 15);
    int cb = ccc * 32 + (lane >> 4) * 8;
    f16x8 pk;
#pragma unroll
    for (int j = 0; j < 8; ++j)
        pk[j] = (_Float16)w_def[(size_t)(o * C_ + cb + j) * 9 + k2];
    *reinterpret_cast<f16x8*>(wfrag + (size_t)idx * 8) = pk;
}

// ---------- prep: w_off -> fp16 MFMA A-frags (M pad 18->32) ----------
__global__ void k_prep_woffrag(const float* __restrict__ w_off, _Float16* __restrict__ wfr) {
    int idx = blockIdx.x * 256 + threadIdx.x;
    if (idx >= 9 * 8 * 2 * 64) return;
    int lane = idx & 63;
    int mfg = (idx >> 6) & 1;
    int ccc = (idx >> 7) & 7;
    int k2 = idx >> 10;
    int o = mfg * 16 + (lane & 15);
    int cb = ccc * 32 + (lane >> 4) * 8;
    f16x8 pk;
#pragma unroll
    for (int j = 0; j < 8; ++j)
        pk[j] = (o < 18) ? (_Float16)w_off[(size_t)(o * C_ + cb + j) * 9 + k2] : (_Float16)0.f;
    *reinterpret_cast<f16x8*>(wfr + (size_t)idx * 8) = pk;
}

// ---------- offset conv via MFMA, no LDS ----------
__global__ __launch_bounds__(256) void k_offconv4(const _Float16* __restrict__ xT,
                                                  const _Float16* __restrict__ wofr,
                                                  const float* __restrict__ b_off,
                                                  float* __restrict__ offs) {
    int bh = blockIdx.x;
    int b = bh & 7, h = bh >> 3;
    int tid = threadIdx.x, lane = tid & 63, wm = tid >> 6;
    int px = wm * 16 + (lane & 15);
    int chl = (lane >> 4) * 8;
    f32x4 acc0 = (f32x4){0.f, 0.f, 0.f, 0.f};
    f32x4 acc1 = (f32x4){0.f, 0.f, 0.f, 0.f};
    const _Float16* xb = xT + (size_t)b * HW_ * C_;
    for (int k2 = 0; k2 < 9; ++k2) {
        int y = h + k2 / 3 - 1;
        int xs = px + k2 % 3 - 1;
        bool v = ((unsigned)y < 64u) && ((unsigned)xs < 64u);
        int yc = y < 0 ? 0 : (y > 63 ? 63 : y);
        int xc = xs < 0 ? 0 : (xs > 63 ? 63 : xs);
        const _Float16* xp = xb + (size_t)(yc * 64 + xc) * C_ + chl;
#pragma unroll
        for (int q = 0; q < 8; ++q) {
            f16x8 bf = *reinterpret_cast<const f16x8*>(xp + q * 32);
            if (!v) bf = (f16x8)(_Float16)0.f;
            const f16x8* wp = reinterpret_cast<const f16x8*>(wofr) +
                              (size_t)((k2 * 8 + q) * 2) * 64 + lane;
            acc0 = __builtin_amdgcn_mfma_f32_16x16x32_f16(wp[0], bf, acc0, 0, 0, 0);
            acc1 = __builtin_amdgcn_mfma_f32_16x16x32_f16(wp[64], bf, acc1, 0, 0, 0);
        }
    }
#pragma unroll
    for (int r = 0; r < 4; ++r) {
        int oc = (lane >> 4) * 4 + r;
        offs[(((size_t)b * 18 + oc) * 64 + h) * 64 + px] = acc0[r] + b_off[oc];
    }
#pragma unroll
    for (int r = 0; r < 4; ++r) {
        int oc = 16 + (lane >> 4) * 4 + r;
        if (oc < 18)
            offs[(((size_t)b * 18 + oc) * 64 + h) * 64 + px] = acc1[r] + b_off[oc];
    }
}

// ---------- deform: LDS row-staged gather + MFMA, N=64, chunk-outer/tap-inner ----------
// Block (b,h): M=256, N=64, K = 8 chunks(32ch) x 9 taps. 3 blocks/CU.
__global__ __launch_bounds__(256, 3) void k_deform6(const _Float16* __restrict__ xT,
                                                    const _Float16* __restrict__ wfrag,
                                                    const float* __restrict__ offs,
                                                    float* __restrict__ out) {
    int blk = blockIdx.x;
    int b = blk & 7, h = blk >> 3;
    int tid = threadIdx.x, lane = tid & 63, wm = tid >> 6;
    int gp = tid & 63, gq = tid >> 6;  // pack role: pixel gp, channel octet gq

    __shared__ float s_py[9][64], s_px[9][64];
    __shared__ __align__(16) _Float16 s_x[7 * 64 * 40];    // rows h-3..h+3, px-stride 40h=80B
    __shared__ __align__(16) _Float16 s_samp[2][64 * 40];  // [px][4 octets], 80B stride

    const _Float16* xb = xT + (size_t)b * HW_ * C_;

    for (int idx = tid; idx < 576; idx += 256) {
        int k2 = idx >> 6, p = idx & 63;
        float dy = offs[(((size_t)b * 18 + k2 * 2 + 0) * 64 + h) * 64 + p];
        float dx = offs[(((size_t)b * 18 + k2 * 2 + 1) * 64 + h) * 64 + p];
        s_py[k2][p] = (float)(h - 1 + k2 / 3) + dy;
        s_px[k2][p] = (float)(p - 1 + k2 % 3) + dx;
    }
    __syncthreads();

    f32x4 acc[4][4];
#pragma unroll
    for (int i = 0; i < 4; ++i)
#pragma unroll
        for (int j = 0; j < 4; ++j) acc[i][j] = (f32x4){0.f, 0.f, 0.f, 0.f};

#define LOADA(DST, T)                                                              \
    {                                                                              \
        const f16x8* wf = reinterpret_cast<const f16x8*>(wfrag) +                  \
                          ((size_t)(T) * 16 + wm * 4) * 64 + lane;                 \
        _Pragma("unroll") for (int mf = 0; mf < 4; ++mf) DST[mf] = wf[mf * 64];    \
    }

#define PACKSTEP(K2, BUF)                                                          \
    {                                                                              \
        float py = s_py[K2][gp], pxx = s_px[K2][gp];                               \
        float y0f = floorf(py), x0f = floorf(pxx);                                 \
        float wy = py - y0f, wx = pxx - x0f;                                       \
        int y0 = (int)y0f, x0 = (int)x0f;                                          \
        float w00 = (1.f - wy) * (1.f - wx), w01 = (1.f - wy) * wx;                \
        float w10 = wy * (1.f - wx), w11 = wy * wx;                                \
        bool vy0 = (unsigned)y0 < 64u, vy1 = (unsigned)(y0 + 1) < 64u;             \
        bool vx0 = (unsigned)x0 < 64u, vx1 = (unsigned)(x0 + 1) < 64u;             \
        if (!(vy0 && vx0)) w00 = 0.f;                                              \
        if (!(vy0 && vx1)) w01 = 0.f;                                              \
        if (!(vy1 && vx0)) w10 = 0.f;                                              \
        if (!(vy1 && vx1)) w11 = 0.f;                                              \
        _Float16 hw00 = (_Float16)w00, hw01 = (_Float16)w01;                       \
        _Float16 hw10 = (_Float16)w10, hw11 = (_Float16)w11;                       \
        int x0c = x0 < 0 ? 0 : (x0 > 63 ? 63 : x0);                                \
        int x1c = (x0 + 1) < 0 ? 0 : ((x0 + 1) > 63 ? 63 : (x0 + 1));              \
        int ry0 = y0 - h + 3;                                                      \
        f16x8 c00, c01, c10, c11;                                                  \
        if (ry0 >= 0 && ry0 <= 5) {                                                \
            const _Float16* base0 = s_x + ry0 * 2560 + gq * 8;                     \
            c00 = *reinterpret_cast<const f16x8*>(base0 + x0c * 40);               \
            c01 = *reinterpret_cast<const f16x8*>(base0 + x1c * 40);               \
            c10 = *reinterpret_cast<const f16x8*>(base0 + 2560 + x0c * 40);        \
            c11 = *reinterpret_cast<const f16x8*>(base0 + 2560 + x1c * 40);        \
        } else {                                                                   \
            int y0c = y0 < 0 ? 0 : (y0 > 63 ? 63 : y0);                            \
            int y1c = (y0 + 1) < 0 ? 0 : ((y0 + 1) > 63 ? 63 : (y0 + 1));          \
            const _Float16* gb = xb + cq * 32 + gq * 8;                            \
            c00 = *reinterpret_cast<const f16x8*>(gb + (size_t)(y0c * 64 + x0c) * C_); \
            c01 = *reinterpret_cast<const f16x8*>(gb + (size_t)(y0c * 64 + x1c) * C_); \
            c10 = *reinterpret_cast<const f16x8*>(gb + (size_t)(y1c * 64 + x0c) * C_); \
            c11 = *reinterpret_cast<const f16x8*>(gb + (size_t)(y1c * 64 + x1c) * C_); \
        }                                                                          \
        f16x8 pk = c00 * hw00 + c01 * hw01 + c10 * hw10 + c11 * hw11;              \
        *reinterpret_cast<f16x8*>(&s_samp[BUF][gp * 40 + gq * 8]) = pk;            \
    }

    f16x8 Ac[4], An[4];
    LOADA(Ac, 0);
#pragma unroll
    for (int mf = 0; mf < 4; ++mf) An[mf] = Ac[mf];

    for (int cq = 0; cq < 8; ++cq) {
        // ---- stage 7 rows x 64px x 32ch of this channel chunk into s_x ----
        {
            int spx = tid >> 2, o = tid & 3;
#pragma unroll
            for (int r = 0; r < 7; ++r) {
                int yr = h - 3 + r;
                yr = yr < 0 ? 0 : (yr > 63 ? 63 : yr);
                f16x8 v = *reinterpret_cast<const f16x8*>(
                    xb + (size_t)(yr * 64 + spx) * C_ + cq * 32 + o * 8);
                *reinterpret_cast<f16x8*>(&s_x[(r * 64 + spx) * 40 + o * 8]) = v;
            }
        }
        asm volatile("s_waitcnt lgkmcnt(0)" ::: "memory");
        __builtin_amdgcn_s_barrier();

        PACKSTEP(0, 0);  // tap 0 samples into buf 0
        asm volatile("s_waitcnt lgkmcnt(0)" ::: "memory");
        __builtin_amdgcn_s_barrier();

#pragma unroll
        for (int k2 = 0; k2 < 9; ++k2) {
            // A-frags for next step (stay in flight under MFMA)
            if (k2 < 8) {
                LOADA(An, (k2 + 1) * 8 + cq);
            } else if (cq < 7) {
                LOADA(An, cq + 1);
            }

            // B-frags for this step
            f16x8 bfr[4];
#pragma unroll
            for (int nf = 0; nf < 4; ++nf) {
                int n = nf * 16 + (lane & 15);
                bfr[nf] = *reinterpret_cast<const f16x8*>(
                    &s_samp[k2 & 1][n * 40 + (lane >> 4) * 8]);
            }

#pragma unroll
            for (int mf = 0; mf < 4; ++mf)
#pragma unroll
                for (int nf = 0; nf < 4; ++nf)
                    acc[mf][nf] = __builtin_amdgcn_mfma_f32_16x16x32_f16(
                        Ac[mf], bfr[nf], acc[mf][nf], 0, 0, 0);

            if (k2 < 8) {
                PACKSTEP(k2 + 1, (k2 + 1) & 1);
            }
#pragma unroll
            for (int mf = 0; mf < 4; ++mf) Ac[mf] = An[mf];

            asm volatile("s_waitcnt lgkmcnt(0)" ::: "memory");
            __builtin_amdgcn_s_barrier();
        }
    }

    float* op = out + (size_t)b * O_ * HW_ + h * 64;
#pragma unroll
    for (int mf = 0; mf < 4; ++mf)
#pragma unroll
        for (int nf = 0; nf < 4; ++nf)
#pragma unroll
            for (int r = 0; r < 4; ++r) {
                int o = wm * 64 + mf * 16 + (lane >> 4) * 4 + r;
                int w = nf * 16 + (lane & 15);
                op[(size_t)o * HW_ + w] = acc[mf][nf][r];
            }
}

extern "C" void kernel_launch(void* const* d_in, const int* in_sizes, int n_in,
                              void* d_out, int out_size, void* d_ws, size_t ws_size,
                              hipStream_t stream) {
    const float* x = (const float*)d_in[0];
    const float* w_off = (const float*)d_in[1];
    const float* b_off = (const float*)d_in[2];
    const float* w_def = (const float*)d_in[3];
    float* out = (float*)d_out;
    char* ws = (char*)d_ws;

    float* offs = (float*)ws;                                            // 2,359,296 B
    _Float16* xT = (_Float16*)(ws + 2359296);                            // 16,777,216 B
    _Float16* wfrag = (_Float16*)(ws + 2359296 + 16777216);              // 1,179,648 B
    _Float16* wofr = (_Float16*)(ws + 2359296 + 16777216 + 1179648);     // 147,456 B

    k_nhwc<<<512, 256, 0, stream>>>(x, xT);
    k_prep_wdef<<<288, 256, 0, stream>>>(w_def, wfrag);
    k_prep_woffrag<<<36, 256, 0, stream>>>(w_off, wofr);
    k_offconv4<<<512, 256, 0, stream>>>(xT, wofr, b_off, offs);
    k_deform6<<<512, 256, 0, stream>>>(xT, wfrag, offs, out);
}